// Round 7
// baseline (435.946 us; speedup 1.0000x reference)
//
#include <hip/hip_runtime.h>

#define LQ 8500

typedef _Float16 half8 __attribute__((ext_vector_type(8)));
typedef _Float16 h2 __attribute__((ext_vector_type(2)));
typedef float f32x4 __attribute__((ext_vector_type(4)));

__device__ __forceinline__ unsigned short f2h(float f) {
    return __builtin_bit_cast(unsigned short, (_Float16)f);
}
__device__ __forceinline__ float hlo(unsigned w) {
    return (float)__builtin_bit_cast(_Float16, (unsigned short)(w & 0xffffu));
}
__device__ __forceinline__ float hhi(unsigned w) {
    return (float)__builtin_bit_cast(_Float16, (unsigned short)(w >> 16));
}
__device__ __forceinline__ unsigned pk2(float a, float b) {
    return (unsigned)f2h(a) | ((unsigned)f2h(b) << 16);
}
__device__ __forceinline__ h2 toh2(unsigned w) { return __builtin_bit_cast(h2, w); }
__device__ __forceinline__ h2 bc2(float f) {
    _Float16 h = (_Float16)f;
    return h2{h, h};
}

// ---------------------------------------------------------------------------
// Kernel 0: weight prep. Wct[384][256] = [Woff|Watt]^T fp16, Wvt = Wval^T,
// Wot = Wout^T fp16, bcat[384] fp32.
// ---------------------------------------------------------------------------
__global__ __launch_bounds__(256) void prep_weights(const float* __restrict__ Woff,
                                                    const float* __restrict__ boff,
                                                    const float* __restrict__ Watt,
                                                    const float* __restrict__ batt,
                                                    const float* __restrict__ Wval,
                                                    const float* __restrict__ Wout,
                                                    unsigned short* __restrict__ Wct,
                                                    unsigned short* __restrict__ Wvt,
                                                    unsigned short* __restrict__ Wot,
                                                    float* __restrict__ bcat) {
    int idx = blockIdx.x * 256 + threadIdx.x;
    if (idx < 98304) {                       // Wct[j][k] = Wcat[k][j]
        int j = idx >> 8, k = idx & 255;
        float v = (j < 256) ? Woff[k * 256 + j] : Watt[k * 128 + (j - 256)];
        Wct[idx] = f2h(v);
    } else if (idx < 98304 + 65536) {        // Wvt[n][k] = Wval[k][n]
        int t = idx - 98304;
        int n = t >> 8, k = t & 255;
        Wvt[t] = f2h(Wval[k * 256 + n]);
    } else if (idx < 98304 + 131072) {       // Wot[n][k] = Wout[k][n]
        int t = idx - 98304 - 65536;
        int n = t >> 8, k = t & 255;
        Wot[t] = f2h(Wout[k * 256 + n]);
    } else if (idx < 98304 + 131072 + 384) {
        int j = idx - 98304 - 131072;
        bcat[j] = (j < 256) ? boff[j] : batt[j - 256];
    }
}

// ---------------------------------------------------------------------------
// MFMA fp16 GEMM, full-K LDS staging: C[M x N] = A[M x 256] @ Bt[N x 256]^T + b.
// Grid: x = col tile (N/128), y = row tile. 256 threads = 4 waves (2x2).
// A-tile [8 ksteps][128 rows][32 k] f16 in 64KB LDS (one barrier); B frags are
// read per k-step straight from global (weights are L2-resident, broadcast).
// ASRC 0: A fp16. 1: A fp32. 2: A = input_flatten fp32, row = g*LQ+pos sums
// frames t2 in [t1-1,t1+1] (predicated adds, unconditional loads).
// OUTMODE 0: fp32 flat N=256. 1: fp16 Vs-plane N=256 (+bias*K(t1)). 2: fp16 flat N=384.
// ---------------------------------------------------------------------------
template <int OUTMODE, int ASRC>
__global__ __launch_bounds__(256) void gemm_f16(const void* __restrict__ Avoid,
                                                const unsigned short* __restrict__ Bt,
                                                const float* __restrict__ bias,
                                                void* __restrict__ Cout, int M) {
    __shared__ char lds[65536];
    const int tid = threadIdx.x;
    const int c0 = blockIdx.x * 128, r0 = blockIdx.y * 128;
    const int wid = tid >> 6, lane = tid & 63;
    const int wr = (wid >> 1) * 64, wc = (wid & 1) * 64;

    // ---- stage full A tile: 4096 chunks of 16B (8 f16), 16 per thread ----
#pragma unroll
    for (int i = 0; i < 16; ++i) {
        int c = i * 256 + tid;
        int t = c >> 9;                  // k-step 0..7
        int row = (c >> 2) & 127;
        int seg = c & 3;
        int koff = t * 32 + seg * 8;
        int ar = r0 + row;
        uint4 va = {0, 0, 0, 0};
        if (ar < M) {
            if (ASRC == 0) {
                va = *reinterpret_cast<const uint4*>(
                    (const unsigned short*)Avoid + (size_t)ar * 256 + koff);
            } else if (ASRC == 1) {
                const float4* ap = reinterpret_cast<const float4*>(
                    (const float*)Avoid + (size_t)ar * 256 + koff);
                float4 a = ap[0], b = ap[1];
                va.x = pk2(a.x, a.y); va.y = pk2(a.z, a.w);
                va.z = pk2(b.x, b.y); va.w = pk2(b.z, b.w);
            } else {
                int g = ar / LQ;
                int pos = ar - g * LQ;
                int t1 = g & 3, n = g >> 2;
                int tp = t1 == 0 ? 0 : t1 - 1;
                int tn = t1 == 3 ? 3 : t1 + 1;
                const float* fb = (const float*)Avoid;
                const float4* pm = reinterpret_cast<const float4*>(
                    fb + ((size_t)(n * 4 + t1) * LQ + pos) * 256 + koff);
                const float4* pp = reinterpret_cast<const float4*>(
                    fb + ((size_t)(n * 4 + tp) * LQ + pos) * 256 + koff);
                const float4* pn = reinterpret_cast<const float4*>(
                    fb + ((size_t)(n * 4 + tn) * LQ + pos) * 256 + koff);
                float4 m0 = pm[0], m1 = pm[1];
                float4 a0 = pp[0], a1 = pp[1];
                float4 b0 = pn[0], b1 = pn[1];
                float fp = (t1 > 0) ? 1.f : 0.f;
                float fn = (t1 < 3) ? 1.f : 0.f;
                float4 s0, s1;
                s0.x = m0.x + fp * a0.x + fn * b0.x;
                s0.y = m0.y + fp * a0.y + fn * b0.y;
                s0.z = m0.z + fp * a0.z + fn * b0.z;
                s0.w = m0.w + fp * a0.w + fn * b0.w;
                s1.x = m1.x + fp * a1.x + fn * b1.x;
                s1.y = m1.y + fp * a1.y + fn * b1.y;
                s1.z = m1.z + fp * a1.z + fn * b1.z;
                s1.w = m1.w + fp * a1.w + fn * b1.w;
                va.x = pk2(s0.x, s0.y); va.y = pk2(s0.z, s0.w);
                va.z = pk2(s1.x, s1.y); va.w = pk2(s1.z, s1.w);
            }
        }
        int byte = (row << 6) + (seg << 4);
        int swz = byte ^ ((row & 7) << 4);
        *reinterpret_cast<uint4*>(lds + t * 8192 + swz) = va;
    }
    __syncthreads();

    // ---- K loop: A frags from LDS, B frags from global ----
    f32x4 acc[4][4] = {};
    for (int t = 0; t < 8; ++t) {
        char* base = lds + t * 8192;
        half8 af[4], bf[4];
#pragma unroll
        for (int j = 0; j < 4; ++j) {
            int rowB = c0 + wc + j * 16 + (lane & 15);
            bf[j] = *reinterpret_cast<const half8*>(
                Bt + (size_t)rowB * 256 + t * 32 + (lane >> 4) * 8);
        }
#pragma unroll
        for (int i = 0; i < 4; ++i) {
            int rowA = wr + i * 16 + (lane & 15);
            int byteA = (rowA << 6) + ((lane >> 4) << 4);
            af[i] = *reinterpret_cast<const half8*>(base + (byteA ^ ((rowA & 7) << 4)));
        }
#pragma unroll
        for (int i = 0; i < 4; ++i)
#pragma unroll
            for (int j = 0; j < 4; ++j)
                acc[i][j] = __builtin_amdgcn_mfma_f32_16x16x32_f16(af[i], bf[j], acc[i][j], 0, 0, 0);
    }

    // ---- epilogue ----
#pragma unroll
    for (int j = 0; j < 4; ++j) {
        int col = c0 + wc + j * 16 + (lane & 15);
        float bv = bias[col];
#pragma unroll
        for (int i = 0; i < 4; ++i) {
#pragma unroll
            for (int r = 0; r < 4; ++r) {
                int row = r0 + wr + i * 16 + (lane >> 4) * 4 + r;
                if (row >= M) continue;
                float v = acc[i][j][r];
                if (OUTMODE == 1) {
                    int g = row / LQ;
                    int pos = row - g * LQ;
                    int t1 = g & 3;
                    float sc = (t1 == 0 || t1 == 3) ? 2.f : 3.f;
                    v += bv * sc;
                    int m = col >> 5, c = col & 31;
                    ((unsigned short*)Cout)[((size_t)(g * 8 + m) * LQ + pos) * 32 + c] = f2h(v);
                } else if (OUTMODE == 2) {
                    ((unsigned short*)Cout)[(size_t)row * 384 + col] = f2h(v + bv);
                } else {
                    ((float*)Cout)[(size_t)row * 256 + col] = v + bv;
                }
            }
        }
    }
}

// ---------------------------------------------------------------------------
// Sampler: batched gather loads (R6) + packed-fp16 accumulation (R5).
// Thread = (q, m, half): 16 channels as 8 h2 accs. Block = 16 q of group g.
// ---------------------------------------------------------------------------
__global__ __launch_bounds__(256) void sample_kernel(const unsigned short* __restrict__ P,
                                                     const float* __restrict__ refp,
                                                     const unsigned short* __restrict__ Vs,
                                                     unsigned short* __restrict__ O16) {
    int tid = threadIdx.x, bid = blockIdx.x;
    int g = bid & 7;
    int q0 = (bid >> 3) * 16;
    int ql = tid >> 4, m = (tid >> 1) & 7, h = tid & 1;
    int q = q0 + ql;
    if (q >= LQ) return;

    const size_t qrow = (size_t)g * LQ + q;

    unsigned ow[16];
    {
        const uint4* po = reinterpret_cast<const uint4*>(P + qrow * 384 + m * 32);
        uint4 a = po[0], b = po[1], c = po[2], d = po[3];
        ow[0] = a.x; ow[1] = a.y; ow[2] = a.z; ow[3] = a.w;
        ow[4] = b.x; ow[5] = b.y; ow[6] = b.z; ow[7] = b.w;
        ow[8] = c.x; ow[9] = c.y; ow[10] = c.z; ow[11] = c.w;
        ow[12] = d.x; ow[13] = d.y; ow[14] = d.z; ow[15] = d.w;
    }
    float wgt[16];
    {
        const uint4* pa = reinterpret_cast<const uint4*>(P + qrow * 384 + 256 + m * 16);
        uint4 a = pa[0], b = pa[1];
        unsigned aw[8] = {a.x, a.y, a.z, a.w, b.x, b.y, b.z, b.w};
#pragma unroll
        for (int j = 0; j < 8; ++j) {
            wgt[j * 2 + 0] = hlo(aw[j]);
            wgt[j * 2 + 1] = hhi(aw[j]);
        }
        float mx = -1e30f;
#pragma unroll
        for (int j = 0; j < 16; ++j) mx = fmaxf(mx, wgt[j]);
        float s = 0.f;
#pragma unroll
        for (int j = 0; j < 16; ++j) { wgt[j] = __expf(wgt[j] - mx); s += wgt[j]; }
        int t1 = g & 3;
        float Kc = (t1 == 0 || t1 == 3) ? 2.f : 3.f;
        float inv = 1.f / (s * Kc);
#pragma unroll
        for (int j = 0; j < 16; ++j) wgt[j] *= inv;
    }

    float rx[4], ry[4];
    {
        const float4* rp = reinterpret_cast<const float4*>(refp + qrow * 8);
        float4 r0 = rp[0], r1 = rp[1];
        rx[0] = r0.x; ry[0] = r0.y; rx[1] = r0.z; ry[1] = r0.w;
        rx[2] = r1.x; ry[2] = r1.y; rx[3] = r1.z; ry[3] = r1.w;
    }

    h2 acc[8];
#pragma unroll
    for (int d = 0; d < 8; ++d) acc[d] = h2{(_Float16)0.f, (_Float16)0.f};

    const unsigned short* vplane = Vs + (size_t)(g * 8 + m) * (LQ * 32) + h * 16;

#pragma unroll 4
    for (int p = 0; p < 16; ++p) {
        const int l = p >> 2;
        const int Wl = 80 >> l;
        const int start = (l == 0) ? 0 : (l == 1) ? 6400 : (l == 2) ? 8000 : 8400;
        const float Wlf = (float)Wl;

        float x = fmaf(rx[l], Wlf, hlo(ow[p])) - 0.5f;
        float y = fmaf(ry[l], Wlf, hhi(ow[p])) - 0.5f;
        float w = wgt[p];

        float xf = floorf(x), yf = floorf(y);
        int x0 = (int)xf, y0 = (int)yf;
        float wx1 = x - xf, wy1 = y - yf;

        int xb = min(max(x0, 0), Wl - 2);
        float wl = (x0 == xb) ? 1.f - wx1 : ((x0 + 1 == xb) ? wx1 : 0.f);
        float wr = (x0 == xb) ? wx1 : ((x0 - 1 == xb) ? 1.f - wx1 : 0.f);

        int yc0 = min(max(y0, 0), Wl - 1);
        float cw0 = (y0 >= 0 && y0 < Wl) ? (1.f - wy1) * w : 0.f;
        int y1i = y0 + 1;
        int yc1 = min(max(y1i, 0), Wl - 1);
        float cw1 = (y1i >= 0 && y1i < Wl) ? wy1 * w : 0.f;

        // batch all 8 loads (2 rows x L/R x 2 uint4)
        const uint4* p0 = reinterpret_cast<const uint4*>(
            vplane + (size_t)(start + yc0 * Wl + xb) * 32);
        const uint4* p1 = reinterpret_cast<const uint4*>(
            vplane + (size_t)(start + yc1 * Wl + xb) * 32);
        uint4 L0a = p0[0], L0b = p0[1], R0a = p0[4], R0b = p0[5];
        uint4 L1a = p1[0], L1b = p1[1], R1a = p1[4], R1b = p1[5];

        h2 c0l = bc2(cw0 * wl), c0r = bc2(cw0 * wr);
        h2 c1l = bc2(cw1 * wl), c1r = bc2(cw1 * wr);

        acc[0] += c0l * toh2(L0a.x) + c0r * toh2(R0a.x) + c1l * toh2(L1a.x) + c1r * toh2(R1a.x);
        acc[1] += c0l * toh2(L0a.y) + c0r * toh2(R0a.y) + c1l * toh2(L1a.y) + c1r * toh2(R1a.y);
        acc[2] += c0l * toh2(L0a.z) + c0r * toh2(R0a.z) + c1l * toh2(L1a.z) + c1r * toh2(R1a.z);
        acc[3] += c0l * toh2(L0a.w) + c0r * toh2(R0a.w) + c1l * toh2(L1a.w) + c1r * toh2(R1a.w);
        acc[4] += c0l * toh2(L0b.x) + c0r * toh2(R0b.x) + c1l * toh2(L1b.x) + c1r * toh2(R1b.x);
        acc[5] += c0l * toh2(L0b.y) + c0r * toh2(R0b.y) + c1l * toh2(L1b.y) + c1r * toh2(R1b.y);
        acc[6] += c0l * toh2(L0b.z) + c0r * toh2(R0b.z) + c1l * toh2(L1b.z) + c1r * toh2(R1b.z);
        acc[7] += c0l * toh2(L0b.w) + c0r * toh2(R0b.w) + c1l * toh2(L1b.w) + c1r * toh2(R1b.w);
    }

    unsigned short* op = O16 + qrow * 256 + m * 32 + h * 16;
    uint4 o0, o1;
    o0.x = __builtin_bit_cast(unsigned, acc[0]);
    o0.y = __builtin_bit_cast(unsigned, acc[1]);
    o0.z = __builtin_bit_cast(unsigned, acc[2]);
    o0.w = __builtin_bit_cast(unsigned, acc[3]);
    o1.x = __builtin_bit_cast(unsigned, acc[4]);
    o1.y = __builtin_bit_cast(unsigned, acc[5]);
    o1.z = __builtin_bit_cast(unsigned, acc[6]);
    o1.w = __builtin_bit_cast(unsigned, acc[7]);
    reinterpret_cast<uint4*>(op)[0] = o0;
    reinterpret_cast<uint4*>(op)[1] = o1;
}

// ---------------------------------------------------------------------------
extern "C" void kernel_launch(void* const* d_in, const int* in_sizes, int n_in,
                              void* d_out, int out_size, void* d_ws, size_t ws_size,
                              hipStream_t stream) {
    const float* query = (const float*)d_in[0];
    const float* refp  = (const float*)d_in[1];
    const float* inp   = (const float*)d_in[2];
    const float* Woff = (const float*)d_in[5];
    const float* boff = (const float*)d_in[6];
    const float* Watt = (const float*)d_in[7];
    const float* batt = (const float*)d_in[8];
    const float* Wval = (const float*)d_in[9];
    const float* bval = (const float*)d_in[10];
    const float* Wout = (const float*)d_in[11];
    const float* bout = (const float*)d_in[12];
    float* out = (float*)d_out;

    // workspace layout (bytes):
    //   Vs   f16 [64 planes][8500][32] @ 0            (34,816,000)
    //   P    f16 [68000][384]          @ 34,816,000   (52,224,000)
    //   O16  f16 [68000][256]          @ 87,040,000   (34,816,000)
    //   Wct  f16 [384][256]            @ 121,856,000  (196,608)
    //   Wvt  f16 [256][256]            @ 122,052,608  (131,072)
    //   Wot  f16 [256][256]            @ 122,183,680  (131,072)
    //   bcat f32 [384]                 @ 122,314,752  (1,536)
    char* base = (char*)d_ws;
    unsigned short* Vs   = (unsigned short*)base;
    unsigned short* P    = (unsigned short*)(base + 34816000);
    unsigned short* O16  = (unsigned short*)(base + 87040000);
    unsigned short* Wct  = (unsigned short*)(base + 121856000);
    unsigned short* Wvt  = (unsigned short*)(base + 122052608);
    unsigned short* Wot  = (unsigned short*)(base + 122183680);
    float* bcat          = (float*)(base + 122314752);

    const int RT = (8 * LQ + 127) / 128;   // 532 row tiles

    // 0) weight prep
    prep_weights<<<dim3(898), 256, 0, stream>>>(Woff, boff, Watt, batt, Wval, Wout,
                                                Wct, Wvt, Wot, bcat);

    // 1) Vs = f16( framesum(input) @ Wval + K(t1)*bval ), plane layout
    gemm_f16<1, 2><<<dim3(2, RT), 256, 0, stream>>>(inp, Wvt, bval, Vs, 8 * LQ);

    // 2) P = f16( query(f32) @ Wcat + bcat )
    gemm_f16<2, 1><<<dim3(3, RT), 256, 0, stream>>>(query, Wct, bcat, P, 8 * LQ);

    // 3) sampler -> O16
    sample_kernel<<<dim3(((LQ + 15) / 16) * 8), 256, 0, stream>>>(P, refp, Vs, O16);

    // 4) d_out = O16 @ Wout + bout (fp32)
    gemm_f16<0, 0><<<dim3(2, RT), 256, 0, stream>>>(O16, Wot, bout, out, 8 * LQ);
}

// Round 8
// 389.836 us; speedup vs baseline: 1.1183x; 1.1183x over previous
//
#include <hip/hip_runtime.h>

#define LQ 8500

typedef _Float16 half8 __attribute__((ext_vector_type(8)));
typedef float f32x4 __attribute__((ext_vector_type(4)));

__device__ __forceinline__ unsigned short f2h(float f) {
    return __builtin_bit_cast(unsigned short, (_Float16)f);
}
__device__ __forceinline__ float hlo(unsigned w) {
    return (float)__builtin_bit_cast(_Float16, (unsigned short)(w & 0xffffu));
}
__device__ __forceinline__ float hhi(unsigned w) {
    return (float)__builtin_bit_cast(_Float16, (unsigned short)(w >> 16));
}
__device__ __forceinline__ unsigned pk2(float a, float b) {
    return (unsigned)f2h(a) | ((unsigned)f2h(b) << 16);
}

// ---------------------------------------------------------------------------
// Kernel 0: weight prep. Wct[384][256] = [Woff|Watt]^T fp16, Wvt = Wval^T,
// Wot = Wout^T fp16, bcat[384] fp32.
// ---------------------------------------------------------------------------
__global__ __launch_bounds__(256) void prep_weights(const float* __restrict__ Woff,
                                                    const float* __restrict__ boff,
                                                    const float* __restrict__ Watt,
                                                    const float* __restrict__ batt,
                                                    const float* __restrict__ Wval,
                                                    const float* __restrict__ Wout,
                                                    unsigned short* __restrict__ Wct,
                                                    unsigned short* __restrict__ Wvt,
                                                    unsigned short* __restrict__ Wot,
                                                    float* __restrict__ bcat) {
    int idx = blockIdx.x * 256 + threadIdx.x;
    if (idx < 98304) {                       // Wct[j][k] = Wcat[k][j]
        int j = idx >> 8, k = idx & 255;
        float v = (j < 256) ? Woff[k * 256 + j] : Watt[k * 128 + (j - 256)];
        Wct[idx] = f2h(v);
    } else if (idx < 98304 + 65536) {        // Wvt[n][k] = Wval[k][n]
        int t = idx - 98304;
        int n = t >> 8, k = t & 255;
        Wvt[t] = f2h(Wval[k * 256 + n]);
    } else if (idx < 98304 + 131072) {       // Wot[n][k] = Wout[k][n]
        int t = idx - 98304 - 65536;
        int n = t >> 8, k = t & 255;
        Wot[t] = f2h(Wout[k * 256 + n]);
    } else if (idx < 98304 + 131072 + 384) {
        int j = idx - 98304 - 131072;
        bcat[j] = (j < 256) ? boff[j] : batt[j - 256];
    }
}

// ---------------------------------------------------------------------------
// MFMA fp16 GEMM, double-buffered (R5-proven): C[M x N] = A[M x 256]@Bt[N x 256]^T.
// 128x128 tile, BK=32, 256 threads = 4 waves (2x2, each 64x64 = 4x4 frags).
// ASRC 0: A fp16 flat. 1: A fp32 flat (convert in staging).
// OUTMODE 0: fp32 flat N=256 (+bias). 2: fp16 flat N=384 (+bias).
//         3: fp16 flat N=256 (no bias).
// ---------------------------------------------------------------------------
template <int OUTMODE, int ASRC>
__global__ __launch_bounds__(256) void gemm_f16(const void* __restrict__ Avoid,
                                                const unsigned short* __restrict__ Bt,
                                                const float* __restrict__ bias,
                                                void* __restrict__ Cout, int M) {
    __shared__ char lds[32768];   // buf b: A @ b*16384, B @ b*16384+8192
    const int tid = threadIdx.x;
    const int r0 = blockIdx.x * 128, c0 = blockIdx.y * 128;
    const int wid = tid >> 6, lane = tid & 63;
    const int wr = (wid >> 1) * 64, wc = (wid & 1) * 64;

    f32x4 acc[4][4] = {};
    uint4 ra[2], rb[2];

#define LOADT(k0)                                                                      \
    {                                                                                  \
        _Pragma("unroll")                                                              \
        for (int cc = 0; cc < 2; ++cc) {                                               \
            int ch = cc * 256 + tid;                                                   \
            int row = ch >> 2, seg = ch & 3;                                           \
            uint4 va = {0, 0, 0, 0};                                                   \
            int ar = r0 + row;                                                         \
            if (ar < M) {                                                              \
                if (ASRC == 0) {                                                       \
                    va = *reinterpret_cast<const uint4*>(                              \
                        (const unsigned short*)Avoid + (size_t)ar * 256 + (k0) + seg * 8); \
                } else {                                                               \
                    const float4* ap = reinterpret_cast<const float4*>(                \
                        (const float*)Avoid + (size_t)ar * 256 + (k0) + seg * 8);      \
                    float4 a = ap[0], b = ap[1];                                       \
                    va.x = pk2(a.x, a.y); va.y = pk2(a.z, a.w);                        \
                    va.z = pk2(b.x, b.y); va.w = pk2(b.z, b.w);                        \
                }                                                                      \
            }                                                                          \
            ra[cc] = va;                                                               \
            rb[cc] = *reinterpret_cast<const uint4*>(Bt + (size_t)(c0 + row) * 256 +   \
                                                     (k0) + seg * 8);                  \
        }                                                                              \
    }

#define STORET(b)                                                                      \
    {                                                                                  \
        _Pragma("unroll")                                                              \
        for (int cc = 0; cc < 2; ++cc) {                                               \
            int ch = cc * 256 + tid;                                                   \
            int row = ch >> 2, seg = ch & 3;                                           \
            int byte = (row << 6) + (seg << 4);                                        \
            int swz = byte ^ ((row & 7) << 4);                                         \
            *reinterpret_cast<uint4*>(lds + (b) * 16384 + swz) = ra[cc];               \
            *reinterpret_cast<uint4*>(lds + (b) * 16384 + 8192 + swz) = rb[cc];        \
        }                                                                              \
    }

    LOADT(0);
    STORET(0);
    __syncthreads();

    for (int t = 0; t < 8; ++t) {
        if (t < 7) LOADT((t + 1) * 32);
        char* base = lds + (t & 1) * 16384;
        half8 af[4], bf[4];
#pragma unroll
        for (int i = 0; i < 4; ++i) {
            int rowA = wr + i * 16 + (lane & 15);
            int byteA = (rowA << 6) + ((lane >> 4) << 4);
            af[i] = *reinterpret_cast<const half8*>(base + (byteA ^ ((rowA & 7) << 4)));
            int rowB = wc + i * 16 + (lane & 15);
            int byteB = (rowB << 6) + ((lane >> 4) << 4);
            bf[i] = *reinterpret_cast<const half8*>(base + 8192 + (byteB ^ ((rowB & 7) << 4)));
        }
#pragma unroll
        for (int i = 0; i < 4; ++i)
#pragma unroll
            for (int j = 0; j < 4; ++j)
                acc[i][j] = __builtin_amdgcn_mfma_f32_16x16x32_f16(af[i], bf[j], acc[i][j], 0, 0, 0);
        if (t < 7) STORET((t + 1) & 1);
        __syncthreads();
    }

#pragma unroll
    for (int j = 0; j < 4; ++j) {
        int col = c0 + wc + j * 16 + (lane & 15);
        float bv = (OUTMODE == 3) ? 0.f : bias[col];
#pragma unroll
        for (int i = 0; i < 4; ++i) {
#pragma unroll
            for (int r = 0; r < 4; ++r) {
                int row = r0 + wr + i * 16 + (lane >> 4) * 4 + r;
                if (row >= M) continue;
                float v = acc[i][j][r];
                if (OUTMODE == 2) {
                    ((unsigned short*)Cout)[(size_t)row * 384 + col] = f2h(v + bv);
                } else if (OUTMODE == 3) {
                    ((unsigned short*)Cout)[(size_t)row * 256 + col] = f2h(v);
                } else {
                    ((float*)Cout)[(size_t)row * 256 + col] = v + bv;
                }
            }
        }
    }
#undef LOADT
#undef STORET
}

// ---------------------------------------------------------------------------
// vsum: Vs plane [(g*8+m)][pos][32] = sum_{t2 in win(t1)} Y[(n*4+t2)*LQ+pos] + K*bval
// Thread handles 8 channels (16B). Grid: x = 16B-chunks (133), y = 64 planes.
// ---------------------------------------------------------------------------
__global__ __launch_bounds__(256) void vsum_kernel(const unsigned short* __restrict__ Y,
                                                   const float* __restrict__ bval,
                                                   unsigned short* __restrict__ Vs) {
    int plane = blockIdx.y;             // g*8 + m
    int g = plane >> 3, m = plane & 7;
    int t1 = g & 3, n = g >> 2;
    int f = blockIdx.x * 256 + threadIdx.x;
    if (f >= LQ * 4) return;
    int pos = f >> 2, c8 = (f & 3) * 8;
    float Kc = (t1 == 0 || t1 == 3) ? 2.f : 3.f;
    const float* bp = bval + m * 32 + c8;
    float acc[8];
#pragma unroll
    for (int j = 0; j < 8; ++j) acc[j] = Kc * bp[j];
    int t2a = t1 == 0 ? 0 : t1 - 1;
    int t2b = t1 == 3 ? 3 : t1 + 1;
    for (int t2 = t2a; t2 <= t2b; ++t2) {
        uint4 v = *reinterpret_cast<const uint4*>(
            Y + ((size_t)(n * 4 + t2) * LQ + pos) * 256 + m * 32 + c8);
        acc[0] += hlo(v.x); acc[1] += hhi(v.x);
        acc[2] += hlo(v.y); acc[3] += hhi(v.y);
        acc[4] += hlo(v.z); acc[5] += hhi(v.z);
        acc[6] += hlo(v.w); acc[7] += hhi(v.w);
    }
    uint4 o;
    o.x = pk2(acc[0], acc[1]); o.y = pk2(acc[2], acc[3]);
    o.z = pk2(acc[4], acc[5]); o.w = pk2(acc[6], acc[7]);
    *reinterpret_cast<uint4*>(Vs + ((size_t)plane * LQ + pos) * 32 + c8) = o;
}

// ---------------------------------------------------------------------------
// Sampler: R6 math (fp32 acc, batched loads) + LDS staging of levels 2,3.
// Block = one (g,m) plane x 128 queries; thread = (q, half): 16 channels.
// Levels 2+3 = positions 8000..8499 (500 recs x 64B = 32KB) staged to LDS.
// bid: g = bid&7 (XCD affinity), m = (bid>>3)&7, qb = bid>>6.
// ---------------------------------------------------------------------------
__global__ __launch_bounds__(256) void sample_kernel(const unsigned short* __restrict__ P,
                                                     const float* __restrict__ refp,
                                                     const unsigned short* __restrict__ Vs,
                                                     unsigned short* __restrict__ O16) {
    __shared__ uint4 vlds4[2000];       // 32000 B

    int tid = threadIdx.x, bid = blockIdx.x;
    int g = bid & 7, m = (bid >> 3) & 7, qb = bid >> 6;
    const unsigned short* vplane0 = Vs + (size_t)(g * 8 + m) * (LQ * 32);

    // ---- stage l2+l3 (coalesced, 2000 x 16B) ----
    {
        const uint4* src = reinterpret_cast<const uint4*>(vplane0 + 8000 * 32);
#pragma unroll
        for (int i = 0; i < 8; ++i) {
            int c = i * 256 + tid;
            if (c < 2000) vlds4[c] = src[c];
        }
    }
    __syncthreads();

    int ql = tid >> 1, h = tid & 1;
    int q = qb * 128 + ql;
    if (q >= LQ) return;

    const size_t qrow = (size_t)g * LQ + q;

    unsigned ow[16];
    {
        const uint4* po = reinterpret_cast<const uint4*>(P + qrow * 384 + m * 32);
        uint4 a = po[0], b = po[1], c = po[2], d = po[3];
        ow[0] = a.x; ow[1] = a.y; ow[2] = a.z; ow[3] = a.w;
        ow[4] = b.x; ow[5] = b.y; ow[6] = b.z; ow[7] = b.w;
        ow[8] = c.x; ow[9] = c.y; ow[10] = c.z; ow[11] = c.w;
        ow[12] = d.x; ow[13] = d.y; ow[14] = d.z; ow[15] = d.w;
    }
    float wgt[16];
    {
        const uint4* pa = reinterpret_cast<const uint4*>(P + qrow * 384 + 256 + m * 16);
        uint4 a = pa[0], b = pa[1];
        unsigned aw[8] = {a.x, a.y, a.z, a.w, b.x, b.y, b.z, b.w};
#pragma unroll
        for (int j = 0; j < 8; ++j) {
            wgt[j * 2 + 0] = hlo(aw[j]);
            wgt[j * 2 + 1] = hhi(aw[j]);
        }
        float mx = -1e30f;
#pragma unroll
        for (int j = 0; j < 16; ++j) mx = fmaxf(mx, wgt[j]);
        float s = 0.f;
#pragma unroll
        for (int j = 0; j < 16; ++j) { wgt[j] = __expf(wgt[j] - mx); s += wgt[j]; }
        int t1 = g & 3;
        float Kc = (t1 == 0 || t1 == 3) ? 2.f : 3.f;
        float inv = 1.f / (s * Kc);
#pragma unroll
        for (int j = 0; j < 16; ++j) wgt[j] *= inv;
    }

    float rx[4], ry[4];
    {
        const float4* rp = reinterpret_cast<const float4*>(refp + qrow * 8);
        float4 r0 = rp[0], r1 = rp[1];
        rx[0] = r0.x; ry[0] = r0.y; rx[1] = r0.z; ry[1] = r0.w;
        rx[2] = r1.x; ry[2] = r1.y; rx[3] = r1.z; ry[3] = r1.w;
    }

    float acc[16];
#pragma unroll
    for (int d = 0; d < 16; ++d) acc[d] = 0.f;

    const unsigned short* vplane = vplane0 + h * 16;
    const unsigned short* lplane = reinterpret_cast<const unsigned short*>(vlds4) + h * 16;

#define SAMPLE_CORE(Wl, GETP0, GETP1)                                                     \
    {                                                                                     \
        float xf = floorf(x), yf = floorf(y);                                             \
        int x0 = (int)xf, y0 = (int)yf;                                                   \
        float wx1 = x - xf, wy1 = y - yf;                                                 \
        int xb = min(max(x0, 0), (Wl)-2);                                                 \
        float wl = (x0 == xb) ? 1.f - wx1 : ((x0 + 1 == xb) ? wx1 : 0.f);                 \
        float wr = (x0 == xb) ? wx1 : ((x0 - 1 == xb) ? 1.f - wx1 : 0.f);                 \
        int yc0 = min(max(y0, 0), (Wl)-1);                                                \
        float cw0 = (y0 >= 0 && y0 < (Wl)) ? (1.f - wy1) * w : 0.f;                       \
        int y1i = y0 + 1;                                                                 \
        int yc1 = min(max(y1i, 0), (Wl)-1);                                               \
        float cw1 = (y1i >= 0 && y1i < (Wl)) ? wy1 * w : 0.f;                             \
        const uint4* p0 = (GETP0);                                                        \
        const uint4* p1 = (GETP1);                                                        \
        uint4 L0a = p0[0], L0b = p0[1], R0a = p0[4], R0b = p0[5];                         \
        uint4 L1a = p1[0], L1b = p1[1], R1a = p1[4], R1b = p1[5];                         \
        float c0l = cw0 * wl, c0r = cw0 * wr;                                             \
        float c1l = cw1 * wl, c1r = cw1 * wr;                                             \
        acc[0]  += c0l * hlo(L0a.x) + c0r * hlo(R0a.x) + c1l * hlo(L1a.x) + c1r * hlo(R1a.x); \
        acc[1]  += c0l * hhi(L0a.x) + c0r * hhi(R0a.x) + c1l * hhi(L1a.x) + c1r * hhi(R1a.x); \
        acc[2]  += c0l * hlo(L0a.y) + c0r * hlo(R0a.y) + c1l * hlo(L1a.y) + c1r * hlo(R1a.y); \
        acc[3]  += c0l * hhi(L0a.y) + c0r * hhi(R0a.y) + c1l * hhi(L1a.y) + c1r * hhi(R1a.y); \
        acc[4]  += c0l * hlo(L0a.z) + c0r * hlo(R0a.z) + c1l * hlo(L1a.z) + c1r * hlo(R1a.z); \
        acc[5]  += c0l * hhi(L0a.z) + c0r * hhi(R0a.z) + c1l * hhi(L1a.z) + c1r * hhi(R1a.z); \
        acc[6]  += c0l * hlo(L0a.w) + c0r * hlo(R0a.w) + c1l * hlo(L1a.w) + c1r * hlo(R1a.w); \
        acc[7]  += c0l * hhi(L0a.w) + c0r * hhi(R0a.w) + c1l * hhi(L1a.w) + c1r * hhi(R1a.w); \
        acc[8]  += c0l * hlo(L0b.x) + c0r * hlo(R0b.x) + c1l * hlo(L1b.x) + c1r * hlo(R1b.x); \
        acc[9]  += c0l * hhi(L0b.x) + c0r * hhi(R0b.x) + c1l * hhi(L1b.x) + c1r * hhi(R1b.x); \
        acc[10] += c0l * hlo(L0b.y) + c0r * hlo(R0b.y) + c1l * hlo(L1b.y) + c1r * hlo(R1b.y); \
        acc[11] += c0l * hhi(L0b.y) + c0r * hhi(R0b.y) + c1l * hhi(L1b.y) + c1r * hhi(R1b.y); \
        acc[12] += c0l * hlo(L0b.z) + c0r * hlo(R0b.z) + c1l * hlo(L1b.z) + c1r * hlo(R1b.z); \
        acc[13] += c0l * hhi(L0b.z) + c0r * hhi(R0b.z) + c1l * hhi(L1b.z) + c1r * hhi(R1b.z); \
        acc[14] += c0l * hlo(L0b.w) + c0r * hlo(R0b.w) + c1l * hlo(L1b.w) + c1r * hlo(R1b.w); \
        acc[15] += c0l * hhi(L0b.w) + c0r * hhi(R0b.w) + c1l * hhi(L1b.w) + c1r * hhi(R1b.w); \
    }

    // ---- levels 0,1: global gathers ----
#pragma unroll
    for (int p = 0; p < 8; ++p) {
        const int l = p >> 2;
        const int Wl = 80 >> l;
        const int start = (l == 0) ? 0 : 6400;
        const float Wlf = (float)Wl;
        float x = fmaf(rx[l], Wlf, hlo(ow[p])) - 0.5f;
        float y = fmaf(ry[l], Wlf, hhi(ow[p])) - 0.5f;
        float w = wgt[p];
        SAMPLE_CORE(Wl,
            reinterpret_cast<const uint4*>(vplane + (size_t)(start + yc0 * Wl + xb) * 32),
            reinterpret_cast<const uint4*>(vplane + (size_t)(start + yc1 * Wl + xb) * 32));
    }
    // ---- levels 2,3: LDS gathers ----
#pragma unroll
    for (int p = 8; p < 16; ++p) {
        const int l = p >> 2;
        const int Wl = 80 >> l;
        const int lbase = (l == 2) ? 0 : 400;
        const float Wlf = (float)Wl;
        float x = fmaf(rx[l], Wlf, hlo(ow[p])) - 0.5f;
        float y = fmaf(ry[l], Wlf, hhi(ow[p])) - 0.5f;
        float w = wgt[p];
        SAMPLE_CORE(Wl,
            reinterpret_cast<const uint4*>(lplane + (lbase + yc0 * Wl + xb) * 32),
            reinterpret_cast<const uint4*>(lplane + (lbase + yc1 * Wl + xb) * 32));
    }
#undef SAMPLE_CORE

    unsigned short* op = O16 + qrow * 256 + m * 32 + h * 16;
    uint4 o0, o1;
    o0.x = pk2(acc[0], acc[1]);   o0.y = pk2(acc[2], acc[3]);
    o0.z = pk2(acc[4], acc[5]);   o0.w = pk2(acc[6], acc[7]);
    o1.x = pk2(acc[8], acc[9]);   o1.y = pk2(acc[10], acc[11]);
    o1.z = pk2(acc[12], acc[13]); o1.w = pk2(acc[14], acc[15]);
    reinterpret_cast<uint4*>(op)[0] = o0;
    reinterpret_cast<uint4*>(op)[1] = o1;
}

// ---------------------------------------------------------------------------
extern "C" void kernel_launch(void* const* d_in, const int* in_sizes, int n_in,
                              void* d_out, int out_size, void* d_ws, size_t ws_size,
                              hipStream_t stream) {
    const float* query = (const float*)d_in[0];
    const float* refp  = (const float*)d_in[1];
    const float* inp   = (const float*)d_in[2];
    const float* Woff = (const float*)d_in[5];
    const float* boff = (const float*)d_in[6];
    const float* Watt = (const float*)d_in[7];
    const float* batt = (const float*)d_in[8];
    const float* Wval = (const float*)d_in[9];
    const float* bval = (const float*)d_in[10];
    const float* Wout = (const float*)d_in[11];
    const float* bout = (const float*)d_in[12];
    float* out = (float*)d_out;

    // workspace layout (bytes):
    //   Y/O16 f16 [68000][256]          @ 0            (34,816,000)  (Y dead after vsum)
    //   Vs    f16 [64 planes][8500][32] @ 34,816,000   (34,816,000)
    //   P     f16 [68000][384]          @ 69,632,000   (52,224,000)
    //   Wct   f16 [384][256]            @ 121,856,000  (196,608)
    //   Wvt   f16 [256][256]            @ 122,052,608  (131,072)
    //   Wot   f16 [256][256]            @ 122,183,680  (131,072)
    //   bcat  f32 [384]                 @ 122,314,752  (1,536)
    char* base = (char*)d_ws;
    unsigned short* Y    = (unsigned short*)base;
    unsigned short* O16  = (unsigned short*)base;            // alias (Y dead)
    unsigned short* Vs   = (unsigned short*)(base + 34816000);
    unsigned short* P    = (unsigned short*)(base + 69632000);
    unsigned short* Wct  = (unsigned short*)(base + 121856000);
    unsigned short* Wvt  = (unsigned short*)(base + 122052608);
    unsigned short* Wot  = (unsigned short*)(base + 122183680);
    float* bcat          = (float*)(base + 122314752);

    const int RT = (8 * LQ + 127) / 128;   // 532 row tiles

    // 0) weight prep
    prep_weights<<<dim3(898), 256, 0, stream>>>(Woff, boff, Watt, batt, Wval, Wout,
                                                Wct, Wvt, Wot, bcat);

    // 1) Y = f16( input_flatten(f32) @ Wval ), per-frame projection (no bias)
    gemm_f16<3, 1><<<dim3(RT, 2), 256, 0, stream>>>(inp, Wvt, bcat, Y, 8 * LQ);

    // 2) Vs planes = sum_{t2} Y + K(t1)*bval
    vsum_kernel<<<dim3((LQ * 4 + 255) / 256, 64), 256, 0, stream>>>(Y, bval, Vs);

    // 3) P = f16( query(f32) @ Wcat + bcat )
    gemm_f16<2, 1><<<dim3(RT, 3), 256, 0, stream>>>(query, Wct, bcat, P, 8 * LQ);

    // 4) sampler -> O16 (aliases Y, dead after vsum)
    sample_kernel<<<dim3(((LQ + 127) / 128) * 64), 256, 0, stream>>>(P, refp, Vs, O16);

    // 5) d_out = O16 @ Wout + bout (fp32)
    gemm_f16<0, 0><<<dim3(RT, 2), 256, 0, stream>>>(O16, Wot, bout, out, 8 * LQ);
}

// Round 9
// 376.906 us; speedup vs baseline: 1.1566x; 1.0343x over previous
//
#include <hip/hip_runtime.h>

#define LQ 8500

typedef _Float16 half8 __attribute__((ext_vector_type(8)));
typedef float f32x4 __attribute__((ext_vector_type(4)));

__device__ __forceinline__ unsigned short f2h(float f) {
    return __builtin_bit_cast(unsigned short, (_Float16)f);
}
__device__ __forceinline__ float hlo(unsigned w) {
    return (float)__builtin_bit_cast(_Float16, (unsigned short)(w & 0xffffu));
}
__device__ __forceinline__ float hhi(unsigned w) {
    return (float)__builtin_bit_cast(_Float16, (unsigned short)(w >> 16));
}
__device__ __forceinline__ unsigned pk2(float a, float b) {
    return (unsigned)f2h(a) | ((unsigned)f2h(b) << 16);
}

// ---------------------------------------------------------------------------
// Kernel 0: weight prep. Wct[384][256] = [Woff|Watt]^T fp16, Wvt = Wval^T,
// Wot = Wout^T fp16, bcat[384] fp32.
// ---------------------------------------------------------------------------
__global__ __launch_bounds__(256) void prep_weights(const float* __restrict__ Woff,
                                                    const float* __restrict__ boff,
                                                    const float* __restrict__ Watt,
                                                    const float* __restrict__ batt,
                                                    const float* __restrict__ Wval,
                                                    const float* __restrict__ Wout,
                                                    unsigned short* __restrict__ Wct,
                                                    unsigned short* __restrict__ Wvt,
                                                    unsigned short* __restrict__ Wot,
                                                    float* __restrict__ bcat) {
    int idx = blockIdx.x * 256 + threadIdx.x;
    if (idx < 98304) {                       // Wct[j][k] = Wcat[k][j]
        int j = idx >> 8, k = idx & 255;
        float v = (j < 256) ? Woff[k * 256 + j] : Watt[k * 128 + (j - 256)];
        Wct[idx] = f2h(v);
    } else if (idx < 98304 + 65536) {        // Wvt[n][k] = Wval[k][n]
        int t = idx - 98304;
        int n = t >> 8, k = t & 255;
        Wvt[t] = f2h(Wval[k * 256 + n]);
    } else if (idx < 98304 + 131072) {       // Wot[n][k] = Wout[k][n]
        int t = idx - 98304 - 65536;
        int n = t >> 8, k = t & 255;
        Wot[t] = f2h(Wout[k * 256 + n]);
    } else if (idx < 98304 + 131072 + 384) {
        int j = idx - 98304 - 131072;
        bcat[j] = (j < 256) ? boff[j] : batt[j - 256];
    }
}

// ---------------------------------------------------------------------------
// MFMA fp16 GEMM, double-buffered: C[M x N] = A[M x 256]@Bt[N x 256]^T.
// 128x128 tile, BK=32, 256 threads = 4 waves (2x2, each 64x64 = 4x4 frags).
// ASRC 0: A fp16 flat. 1: A fp32 flat (convert in staging).
// OUTMODE 0: fp32 flat N=256 (+bias). 2: fp16 flat N=384 (+bias).
//         3: fp16 flat N=256 (no bias).
// ---------------------------------------------------------------------------
template <int OUTMODE, int ASRC>
__global__ __launch_bounds__(256) void gemm_f16(const void* __restrict__ Avoid,
                                                const unsigned short* __restrict__ Bt,
                                                const float* __restrict__ bias,
                                                void* __restrict__ Cout, int M) {
    __shared__ char lds[32768];   // buf b: A @ b*16384, B @ b*16384+8192
    const int tid = threadIdx.x;
    const int r0 = blockIdx.x * 128, c0 = blockIdx.y * 128;
    const int wid = tid >> 6, lane = tid & 63;
    const int wr = (wid >> 1) * 64, wc = (wid & 1) * 64;

    f32x4 acc[4][4] = {};
    uint4 ra[2], rb[2];

#define LOADT(k0)                                                                      \
    {                                                                                  \
        _Pragma("unroll")                                                              \
        for (int cc = 0; cc < 2; ++cc) {                                               \
            int ch = cc * 256 + tid;                                                   \
            int row = ch >> 2, seg = ch & 3;                                           \
            uint4 va = {0, 0, 0, 0};                                                   \
            int ar = r0 + row;                                                         \
            if (ar < M) {                                                              \
                if (ASRC == 0) {                                                       \
                    va = *reinterpret_cast<const uint4*>(                              \
                        (const unsigned short*)Avoid + (size_t)ar * 256 + (k0) + seg * 8); \
                } else {                                                               \
                    const float4* ap = reinterpret_cast<const float4*>(                \
                        (const float*)Avoid + (size_t)ar * 256 + (k0) + seg * 8);      \
                    float4 a = ap[0], b = ap[1];                                       \
                    va.x = pk2(a.x, a.y); va.y = pk2(a.z, a.w);                        \
                    va.z = pk2(b.x, b.y); va.w = pk2(b.z, b.w);                        \
                }                                                                      \
            }                                                                          \
            ra[cc] = va;                                                               \
            rb[cc] = *reinterpret_cast<const uint4*>(Bt + (size_t)(c0 + row) * 256 +   \
                                                     (k0) + seg * 8);                  \
        }                                                                              \
    }

#define STORET(b)                                                                      \
    {                                                                                  \
        _Pragma("unroll")                                                              \
        for (int cc = 0; cc < 2; ++cc) {                                               \
            int ch = cc * 256 + tid;                                                   \
            int row = ch >> 2, seg = ch & 3;                                           \
            int byte = (row << 6) + (seg << 4);                                        \
            int swz = byte ^ ((row & 7) << 4);                                         \
            *reinterpret_cast<uint4*>(lds + (b) * 16384 + swz) = ra[cc];               \
            *reinterpret_cast<uint4*>(lds + (b) * 16384 + 8192 + swz) = rb[cc];        \
        }                                                                              \
    }

    LOADT(0);
    STORET(0);
    __syncthreads();

    for (int t = 0; t < 8; ++t) {
        if (t < 7) LOADT((t + 1) * 32);
        char* base = lds + (t & 1) * 16384;
        half8 af[4], bf[4];
#pragma unroll
        for (int i = 0; i < 4; ++i) {
            int rowA = wr + i * 16 + (lane & 15);
            int byteA = (rowA << 6) + ((lane >> 4) << 4);
            af[i] = *reinterpret_cast<const half8*>(base + (byteA ^ ((rowA & 7) << 4)));
            int rowB = wc + i * 16 + (lane & 15);
            int byteB = (rowB << 6) + ((lane >> 4) << 4);
            bf[i] = *reinterpret_cast<const half8*>(base + 8192 + (byteB ^ ((rowB & 7) << 4)));
        }
#pragma unroll
        for (int i = 0; i < 4; ++i)
#pragma unroll
            for (int j = 0; j < 4; ++j)
                acc[i][j] = __builtin_amdgcn_mfma_f32_16x16x32_f16(af[i], bf[j], acc[i][j], 0, 0, 0);
        if (t < 7) STORET((t + 1) & 1);
        __syncthreads();
    }

#pragma unroll
    for (int j = 0; j < 4; ++j) {
        int col = c0 + wc + j * 16 + (lane & 15);
        float bv = (OUTMODE == 3) ? 0.f : bias[col];
#pragma unroll
        for (int i = 0; i < 4; ++i) {
#pragma unroll
            for (int r = 0; r < 4; ++r) {
                int row = r0 + wr + i * 16 + (lane >> 4) * 4 + r;
                if (row >= M) continue;
                float v = acc[i][j][r];
                if (OUTMODE == 2) {
                    ((unsigned short*)Cout)[(size_t)row * 384 + col] = f2h(v + bv);
                } else if (OUTMODE == 3) {
                    ((unsigned short*)Cout)[(size_t)row * 256 + col] = f2h(v);
                } else {
                    ((float*)Cout)[(size_t)row * 256 + col] = v + bv;
                }
            }
        }
    }
#undef LOADT
#undef STORET
}

// ---------------------------------------------------------------------------
// vsum: Vs plane [(g*8+m)][pos][32] = sum_{t2 in win(t1)} Y[(n*4+t2)*LQ+pos] + K*bval
// ---------------------------------------------------------------------------
__global__ __launch_bounds__(256) void vsum_kernel(const unsigned short* __restrict__ Y,
                                                   const float* __restrict__ bval,
                                                   unsigned short* __restrict__ Vs) {
    int plane = blockIdx.y;             // g*8 + m
    int g = plane >> 3, m = plane & 7;
    int t1 = g & 3, n = g >> 2;
    int f = blockIdx.x * 256 + threadIdx.x;
    if (f >= LQ * 4) return;
    int pos = f >> 2, c8 = (f & 3) * 8;
    float Kc = (t1 == 0 || t1 == 3) ? 2.f : 3.f;
    const float* bp = bval + m * 32 + c8;
    float acc[8];
#pragma unroll
    for (int j = 0; j < 8; ++j) acc[j] = Kc * bp[j];
    int t2a = t1 == 0 ? 0 : t1 - 1;
    int t2b = t1 == 3 ? 3 : t1 + 1;
    for (int t2 = t2a; t2 <= t2b; ++t2) {
        uint4 v = *reinterpret_cast<const uint4*>(
            Y + ((size_t)(n * 4 + t2) * LQ + pos) * 256 + m * 32 + c8);
        acc[0] += hlo(v.x); acc[1] += hhi(v.x);
        acc[2] += hlo(v.y); acc[3] += hhi(v.y);
        acc[4] += hlo(v.z); acc[5] += hhi(v.z);
        acc[6] += hlo(v.w); acc[7] += hhi(v.w);
    }
    uint4 o;
    o.x = pk2(acc[0], acc[1]); o.y = pk2(acc[2], acc[3]);
    o.z = pk2(acc[4], acc[5]); o.w = pk2(acc[6], acc[7]);
    *reinterpret_cast<uint4*>(Vs + ((size_t)plane * LQ + pos) * 32 + c8) = o;
}

// ---------------------------------------------------------------------------
// Sampler: R6 structure (fp32 acc, batched loads, no LDS) + 1-point software
// pipeline: issue point p+1's 8 loads before accumulating point p (two named
// register sets A/B, fully static indexing).
// Thread = (q, m, half): 16 channels. Block = 16 q x 8 m x 2 half of group g.
// ---------------------------------------------------------------------------
__global__ __launch_bounds__(256) void sample_kernel(const unsigned short* __restrict__ P,
                                                     const float* __restrict__ refp,
                                                     const unsigned short* __restrict__ Vs,
                                                     unsigned short* __restrict__ O16) {
    int tid = threadIdx.x, bid = blockIdx.x;
    int g = bid & 7;
    int q0 = (bid >> 3) * 16;
    int ql = tid >> 4, m = (tid >> 1) & 7, h = tid & 1;
    int q = q0 + ql;
    if (q >= LQ) return;

    const size_t qrow = (size_t)g * LQ + q;

    unsigned ow[16];
    {
        const uint4* po = reinterpret_cast<const uint4*>(P + qrow * 384 + m * 32);
        uint4 a = po[0], b = po[1], c = po[2], d = po[3];
        ow[0] = a.x; ow[1] = a.y; ow[2] = a.z; ow[3] = a.w;
        ow[4] = b.x; ow[5] = b.y; ow[6] = b.z; ow[7] = b.w;
        ow[8] = c.x; ow[9] = c.y; ow[10] = c.z; ow[11] = c.w;
        ow[12] = d.x; ow[13] = d.y; ow[14] = d.z; ow[15] = d.w;
    }
    float wgt[16];
    {
        const uint4* pa = reinterpret_cast<const uint4*>(P + qrow * 384 + 256 + m * 16);
        uint4 a = pa[0], b = pa[1];
        unsigned aw[8] = {a.x, a.y, a.z, a.w, b.x, b.y, b.z, b.w};
#pragma unroll
        for (int j = 0; j < 8; ++j) {
            wgt[j * 2 + 0] = hlo(aw[j]);
            wgt[j * 2 + 1] = hhi(aw[j]);
        }
        float mx = -1e30f;
#pragma unroll
        for (int j = 0; j < 16; ++j) mx = fmaxf(mx, wgt[j]);
        float s = 0.f;
#pragma unroll
        for (int j = 0; j < 16; ++j) { wgt[j] = __expf(wgt[j] - mx); s += wgt[j]; }
        int t1 = g & 3;
        float Kc = (t1 == 0 || t1 == 3) ? 2.f : 3.f;
        float inv = 1.f / (s * Kc);
#pragma unroll
        for (int j = 0; j < 16; ++j) wgt[j] *= inv;
    }

    float rx[4], ry[4];
    {
        const float4* rp = reinterpret_cast<const float4*>(refp + qrow * 8);
        float4 r0 = rp[0], r1 = rp[1];
        rx[0] = r0.x; ry[0] = r0.y; rx[1] = r0.z; ry[1] = r0.w;
        rx[2] = r1.x; ry[2] = r1.y; rx[3] = r1.z; ry[3] = r1.w;
    }

    float acc[16];
#pragma unroll
    for (int d = 0; d < 16; ++d) acc[d] = 0.f;

    const unsigned short* vplane = Vs + (size_t)(g * 8 + m) * (LQ * 32) + h * 16;

    // --- pipeline register sets ---
    const uint4 *Ap0, *Ap1, *Bp0, *Bp1;
    float Ac0l, Ac0r, Ac1l, Ac1r, Bc0l, Bc0r, Bc1l, Bc1r;
    uint4 AL0a, AL0b, AR0a, AR0b, AL1a, AL1b, AR1a, AR1b;
    uint4 BL0a, BL0b, BR0a, BR0b, BL1a, BL1b, BR1a, BR1b;

#define PREP(p, S)                                                                     \
    {                                                                                  \
        const int l = (p) >> 2;                                                        \
        const int Wl = 80 >> l;                                                        \
        const int start = (l == 0) ? 0 : (l == 1) ? 6400 : (l == 2) ? 8000 : 8400;     \
        const float Wlf = (float)Wl;                                                   \
        float x = fmaf(rx[l], Wlf, hlo(ow[p])) - 0.5f;                                 \
        float y = fmaf(ry[l], Wlf, hhi(ow[p])) - 0.5f;                                 \
        float w = wgt[p];                                                              \
        float xf = floorf(x), yf = floorf(y);                                          \
        int x0 = (int)xf, y0 = (int)yf;                                                \
        float wx1 = x - xf, wy1 = y - yf;                                              \
        int xb = min(max(x0, 0), Wl - 2);                                              \
        float wl_ = (x0 == xb) ? 1.f - wx1 : ((x0 + 1 == xb) ? wx1 : 0.f);             \
        float wr_ = (x0 == xb) ? wx1 : ((x0 - 1 == xb) ? 1.f - wx1 : 0.f);             \
        int yc0 = min(max(y0, 0), Wl - 1);                                             \
        float cw0 = (y0 >= 0 && y0 < Wl) ? (1.f - wy1) * w : 0.f;                      \
        int y1i = y0 + 1;                                                              \
        int yc1 = min(max(y1i, 0), Wl - 1);                                            \
        float cw1 = (y1i >= 0 && y1i < Wl) ? wy1 * w : 0.f;                            \
        S##p0 = reinterpret_cast<const uint4*>(vplane + (size_t)(start + yc0 * Wl + xb) * 32); \
        S##p1 = reinterpret_cast<const uint4*>(vplane + (size_t)(start + yc1 * Wl + xb) * 32); \
        S##c0l = cw0 * wl_; S##c0r = cw0 * wr_;                                        \
        S##c1l = cw1 * wl_; S##c1r = cw1 * wr_;                                        \
    }

#define ISSUE(S)                                                                       \
    S##L0a = S##p0[0]; S##L0b = S##p0[1]; S##R0a = S##p0[4]; S##R0b = S##p0[5];        \
    S##L1a = S##p1[0]; S##L1b = S##p1[1]; S##R1a = S##p1[4]; S##R1b = S##p1[5];

#define ACCUM(S)                                                                       \
    {                                                                                  \
        float c0l = S##c0l, c0r = S##c0r, c1l = S##c1l, c1r = S##c1r;                  \
        acc[0]  += c0l * hlo(S##L0a.x) + c0r * hlo(S##R0a.x) + c1l * hlo(S##L1a.x) + c1r * hlo(S##R1a.x); \
        acc[1]  += c0l * hhi(S##L0a.x) + c0r * hhi(S##R0a.x) + c1l * hhi(S##L1a.x) + c1r * hhi(S##R1a.x); \
        acc[2]  += c0l * hlo(S##L0a.y) + c0r * hlo(S##R0a.y) + c1l * hlo(S##L1a.y) + c1r * hlo(S##R1a.y); \
        acc[3]  += c0l * hhi(S##L0a.y) + c0r * hhi(S##R0a.y) + c1l * hhi(S##L1a.y) + c1r * hhi(S##R1a.y); \
        acc[4]  += c0l * hlo(S##L0a.z) + c0r * hlo(S##R0a.z) + c1l * hlo(S##L1a.z) + c1r * hlo(S##R1a.z); \
        acc[5]  += c0l * hhi(S##L0a.z) + c0r * hhi(S##R0a.z) + c1l * hhi(S##L1a.z) + c1r * hhi(S##R1a.z); \
        acc[6]  += c0l * hlo(S##L0a.w) + c0r * hlo(S##R0a.w) + c1l * hlo(S##L1a.w) + c1r * hlo(S##R1a.w); \
        acc[7]  += c0l * hhi(S##L0a.w) + c0r * hhi(S##R0a.w) + c1l * hhi(S##L1a.w) + c1r * hhi(S##R1a.w); \
        acc[8]  += c0l * hlo(S##L0b.x) + c0r * hlo(S##R0b.x) + c1l * hlo(S##L1b.x) + c1r * hlo(S##R1b.x); \
        acc[9]  += c0l * hhi(S##L0b.x) + c0r * hhi(S##R0b.x) + c1l * hhi(S##L1b.x) + c1r * hhi(S##R1b.x); \
        acc[10] += c0l * hlo(S##L0b.y) + c0r * hlo(S##R0b.y) + c1l * hlo(S##L1b.y) + c1r * hlo(S##R1b.y); \
        acc[11] += c0l * hhi(S##L0b.y) + c0r * hhi(S##R0b.y) + c1l * hhi(S##L1b.y) + c1r * hhi(S##R1b.y); \
        acc[12] += c0l * hlo(S##L0b.z) + c0r * hlo(S##R0b.z) + c1l * hlo(S##L1b.z) + c1r * hlo(S##R1b.z); \
        acc[13] += c0l * hhi(S##L0b.z) + c0r * hhi(S##R0b.z) + c1l * hhi(S##L1b.z) + c1r * hhi(S##R1b.z); \
        acc[14] += c0l * hlo(S##L0b.w) + c0r * hlo(S##R0b.w) + c1l * hlo(S##L1b.w) + c1r * hlo(S##R1b.w); \
        acc[15] += c0l * hhi(S##L0b.w) + c0r * hhi(S##R0b.w) + c1l * hhi(S##L1b.w) + c1r * hhi(S##R1b.w); \
    }

    PREP(0, A) ISSUE(A)
#pragma unroll
    for (int p = 0; p < 16; p += 2) {
        PREP(p + 1, B) ISSUE(B)
        ACCUM(A)
        if (p + 2 < 16) { PREP(p + 2, A) ISSUE(A) }
        ACCUM(B)
    }
#undef PREP
#undef ISSUE
#undef ACCUM

    unsigned short* op = O16 + qrow * 256 + m * 32 + h * 16;
    uint4 o0, o1;
    o0.x = pk2(acc[0], acc[1]);   o0.y = pk2(acc[2], acc[3]);
    o0.z = pk2(acc[4], acc[5]);   o0.w = pk2(acc[6], acc[7]);
    o1.x = pk2(acc[8], acc[9]);   o1.y = pk2(acc[10], acc[11]);
    o1.z = pk2(acc[12], acc[13]); o1.w = pk2(acc[14], acc[15]);
    reinterpret_cast<uint4*>(op)[0] = o0;
    reinterpret_cast<uint4*>(op)[1] = o1;
}

// ---------------------------------------------------------------------------
extern "C" void kernel_launch(void* const* d_in, const int* in_sizes, int n_in,
                              void* d_out, int out_size, void* d_ws, size_t ws_size,
                              hipStream_t stream) {
    const float* query = (const float*)d_in[0];
    const float* refp  = (const float*)d_in[1];
    const float* inp   = (const float*)d_in[2];
    const float* Woff = (const float*)d_in[5];
    const float* boff = (const float*)d_in[6];
    const float* Watt = (const float*)d_in[7];
    const float* batt = (const float*)d_in[8];
    const float* Wval = (const float*)d_in[9];
    const float* bval = (const float*)d_in[10];
    const float* Wout = (const float*)d_in[11];
    const float* bout = (const float*)d_in[12];
    float* out = (float*)d_out;

    // workspace layout (bytes):
    //   Y/O16 f16 [68000][256]          @ 0            (34,816,000)  (Y dead after vsum)
    //   Vs    f16 [64 planes][8500][32] @ 34,816,000   (34,816,000)
    //   P     f16 [68000][384]          @ 69,632,000   (52,224,000)
    //   Wct   f16 [384][256]            @ 121,856,000  (196,608)
    //   Wvt   f16 [256][256]            @ 122,052,608  (131,072)
    //   Wot   f16 [256][256]            @ 122,183,680  (131,072)
    //   bcat  f32 [384]                 @ 122,314,752  (1,536)
    char* base = (char*)d_ws;
    unsigned short* Y    = (unsigned short*)base;
    unsigned short* O16  = (unsigned short*)base;            // alias (Y dead)
    unsigned short* Vs   = (unsigned short*)(base + 34816000);
    unsigned short* P    = (unsigned short*)(base + 69632000);
    unsigned short* Wct  = (unsigned short*)(base + 121856000);
    unsigned short* Wvt  = (unsigned short*)(base + 122052608);
    unsigned short* Wot  = (unsigned short*)(base + 122183680);
    float* bcat          = (float*)(base + 122314752);

    const int RT = (8 * LQ + 127) / 128;   // 532 row tiles

    // 0) weight prep
    prep_weights<<<dim3(898), 256, 0, stream>>>(Woff, boff, Watt, batt, Wval, Wout,
                                                Wct, Wvt, Wot, bcat);

    // 1) Y = f16( input_flatten(f32) @ Wval ), per-frame projection (no bias)
    gemm_f16<3, 1><<<dim3(RT, 2), 256, 0, stream>>>(inp, Wvt, bcat, Y, 8 * LQ);

    // 2) Vs planes = sum_{t2} Y + K(t1)*bval
    vsum_kernel<<<dim3((LQ * 4 + 255) / 256, 64), 256, 0, stream>>>(Y, bval, Vs);

    // 3) P = f16( query(f32) @ Wcat + bcat )
    gemm_f16<2, 1><<<dim3(RT, 3), 256, 0, stream>>>(query, Wct, bcat, P, 8 * LQ);

    // 4) sampler -> O16 (aliases Y, dead after vsum)
    sample_kernel<<<dim3(((LQ + 15) / 16) * 8), 256, 0, stream>>>(P, refp, Vs, O16);

    // 5) d_out = O16 @ Wout + bout (fp32)
    gemm_f16<0, 0><<<dim3(RT, 2), 256, 0, stream>>>(O16, Wot, bout, out, 8 * LQ);
}